// Round 1
// baseline (644.187 us; speedup 1.0000x reference)
//
#include <hip/hip_runtime.h>
#include <cstddef>

// Problem constants (n=2, c=128, h=w=96, hid=256, P=5, heads=8, d_k=16)
constexpr int Cc = 128;
constexpr int Hh = 96;
constexpr int Ww = 96;
constexpr int HW = Hh * Ww;      // 9216 pixels per image
constexpr int Nn = 2;

// ---------------------------------------------------------------------------
// Generic fp32 GEMM over pixels: Y[z][m][p] = sum_k Wm[m][k] * X[z][k][p]
// Optional bias / leaky-relu / residual-add / per-batch sum&sumsq reduction.
// Block: 256 threads -> tile 64 oc x 128 pixels. K staged in 16-chunks in LDS.
// ---------------------------------------------------------------------------
template<bool BIAS, bool LRELU, bool RESID, bool REDUCE>
__global__ void __launch_bounds__(256)
gemm_k(const float* __restrict__ Wm, const float* __restrict__ X,
       const float* __restrict__ bias, const float* __restrict__ resid,
       float* __restrict__ Y, float* __restrict__ sums,
       int M, int K, int NP)
{
    __shared__ float wlds[16 * 64];    // [k][oc]  (transposed for b128 reads)
    __shared__ float xlds[16 * 128];   // [k][pix]
    __shared__ float red[8];

    const int tid = threadIdx.x;
    const int z  = blockIdx.z;
    const int m0 = blockIdx.y * 64;
    const int p0 = blockIdx.x * 128;
    const float* Xz = X + (size_t)z * K * NP;

    const int tx = tid & 31;   // pixel quad
    const int ty = tid >> 5;   // oc octet

    float acc[8][4];
#pragma unroll
    for (int o = 0; o < 8; ++o)
#pragma unroll
        for (int j = 0; j < 4; ++j) acc[o][j] = 0.f;

    const int wrow = tid >> 2, wkq = tid & 3;

    for (int k0 = 0; k0 < K; k0 += 16) {
        // issue global loads for this chunk first (overlap with prior compute)
        float4 wv  = *(const float4*)&Wm[(size_t)(m0 + wrow) * K + k0 + wkq * 4];
        float4 xv0 = *(const float4*)&Xz[(size_t)(k0 + ty) * NP + p0 + tx * 4];
        float4 xv1 = *(const float4*)&Xz[(size_t)(k0 + 8 + ty) * NP + p0 + tx * 4];
        __syncthreads();   // previous chunk fully consumed
        wlds[(wkq * 4 + 0) * 64 + wrow] = wv.x;
        wlds[(wkq * 4 + 1) * 64 + wrow] = wv.y;
        wlds[(wkq * 4 + 2) * 64 + wrow] = wv.z;
        wlds[(wkq * 4 + 3) * 64 + wrow] = wv.w;
        *(float4*)&xlds[ty * 128 + tx * 4]       = xv0;
        *(float4*)&xlds[(ty + 8) * 128 + tx * 4] = xv1;
        __syncthreads();
#pragma unroll
        for (int kk = 0; kk < 16; ++kk) {
            float4 xv = *(float4*)&xlds[kk * 128 + tx * 4];
            float4 wa = *(float4*)&wlds[kk * 64 + ty * 8];
            float4 wb = *(float4*)&wlds[kk * 64 + ty * 8 + 4];
            float wr[8] = {wa.x, wa.y, wa.z, wa.w, wb.x, wb.y, wb.z, wb.w};
#pragma unroll
            for (int o = 0; o < 8; ++o) {
                acc[o][0] = fmaf(wr[o], xv.x, acc[o][0]);
                acc[o][1] = fmaf(wr[o], xv.y, acc[o][1]);
                acc[o][2] = fmaf(wr[o], xv.z, acc[o][2]);
                acc[o][3] = fmaf(wr[o], xv.w, acc[o][3]);
            }
        }
    }

    float lsum = 0.f, lsq = 0.f;
#pragma unroll
    for (int o = 0; o < 8; ++o) {
        const int oc = m0 + ty * 8 + o;
        float t0 = acc[o][0], t1 = acc[o][1], t2 = acc[o][2], t3 = acc[o][3];
        if (BIAS) {
            float bv = bias[oc];
            t0 += bv; t1 += bv; t2 += bv; t3 += bv;
        }
        if (LRELU) {
            t0 = t0 >= 0.f ? t0 : 0.2f * t0;
            t1 = t1 >= 0.f ? t1 : 0.2f * t1;
            t2 = t2 >= 0.f ? t2 : 0.2f * t2;
            t3 = t3 >= 0.f ? t3 : 0.2f * t3;
        }
        if (RESID) {
            float4 rv = *(const float4*)&resid[((size_t)z * M + oc) * NP + p0 + tx * 4];
            t0 += rv.x; t1 += rv.y; t2 += rv.z; t3 += rv.w;
        }
        if (REDUCE) {
            lsum += t0 + t1 + t2 + t3;
            lsq  += t0 * t0 + t1 * t1 + t2 * t2 + t3 * t3;
        }
        float4 ov = make_float4(t0, t1, t2, t3);
        *(float4*)&Y[((size_t)z * M + oc) * NP + p0 + tx * 4] = ov;
    }

    if (REDUCE) {
#pragma unroll
        for (int m = 1; m < 64; m <<= 1) {
            lsum += __shfl_xor(lsum, m, 64);
            lsq  += __shfl_xor(lsq,  m, 64);
        }
        if ((tid & 63) == 0) {
            red[(tid >> 6) * 2]     = lsum;
            red[(tid >> 6) * 2 + 1] = lsq;
        }
        __syncthreads();
        if (tid == 0) {
            atomicAdd(&sums[z * 2 + 0], red[0] + red[2] + red[4] + red[6]);
            atomicAdd(&sums[z * 2 + 1], red[1] + red[3] + red[5] + red[7]);
        }
    }
}

// ---------------------------------------------------------------------------
// Deformable window attention, one wave per pixel.
// lane = head(3b) x slot(3b); each lane owns channels ch0=head*16+slot*2, ch0+1.
// All 25 samples share fractional weights; corners live in a 6x6 patch.
//   qk[r][c]   = sum_d q_d * K_d[patch]     (per head, via 8-lane butterfly)
//   logits[p]  = 4-tap bilinear of qk
//   wsum[r][c] = attn spread back through the taps
//   out_d      = sum_{r,c} V_d[patch] * wsum
// OOB patch elements masked to zero == grid_sample zeros padding.
// ---------------------------------------------------------------------------
__global__ void __launch_bounds__(256)
attn_kernel(const float* __restrict__ q, const float* __restrict__ k,
            const float* __restrict__ v, const float* __restrict__ df,
            float* __restrict__ out)
{
    const int wid  = blockIdx.x * 4 + (threadIdx.x >> 6);
    const int lane = threadIdx.x & 63;
    const int b = wid / HW;
    const int pix = wid % HW;
    const int y = pix / Ww;
    const int x = pix % Ww;
    const int head = lane >> 3;
    const int slot = lane & 7;
    const int ch0 = head * 16 + slot * 2;

    const float dx = df[((size_t)b * 2 + 0) * HW + pix];
    const float dy = df[((size_t)b * 2 + 1) * HW + pix];
    const float flx = floorf(dx), fly = floorf(dy);
    const int bx = x - 2 + (int)flx;
    const int by = y - 2 + (int)fly;
    const float wx1 = dx - flx, wx0 = 1.f - wx1;
    const float wy1 = dy - fly, wy0 = 1.f - wy1;

    const float qs0 = q[((size_t)b * Cc + ch0) * HW + pix] * 0.25f;
    const float qs1 = q[((size_t)b * Cc + ch0 + 1) * HW + pix] * 0.25f;

    const float* k0p = k + ((size_t)b * Cc + ch0) * HW;
    const float* k1p = k0p + HW;

    float qk[36];
#pragma unroll
    for (int r = 0; r < 6; ++r) {
        const int yr = by + r;
        const bool rv = (yr >= 0) & (yr < Hh);
        const int yc = min(max(yr, 0), Hh - 1);
#pragma unroll
        for (int c = 0; c < 6; ++c) {
            const int xc = bx + c;
            const bool cv = rv & (xc >= 0) & (xc < Ww);
            const int xcc = min(max(xc, 0), Ww - 1);
            const float m = cv ? 1.f : 0.f;
            const int off = yc * Ww + xcc;
            qk[r * 6 + c] = (qs0 * k0p[off] + qs1 * k1p[off]) * m;
        }
    }
    // reduce partial qk over the 8 slots of this head
#pragma unroll
    for (int m = 1; m <= 4; m <<= 1) {
#pragma unroll
        for (int i = 0; i < 36; ++i)
            qk[i] += __shfl_xor(qk[i], m, 64);
    }

    // logits + online max
    float a[25];
    float mx = -1e30f;
#pragma unroll
    for (int py = 0; py < 5; ++py)
#pragma unroll
        for (int px = 0; px < 5; ++px) {
            float t = wy0 * (wx0 * qk[py * 6 + px]       + wx1 * qk[py * 6 + px + 1])
                    + wy1 * (wx0 * qk[(py + 1) * 6 + px] + wx1 * qk[(py + 1) * 6 + px + 1]);
            a[py * 5 + px] = t;
            mx = fmaxf(mx, t);
        }
    float s = 0.f;
#pragma unroll
    for (int i = 0; i < 25; ++i) { a[i] = __expf(a[i] - mx); s += a[i]; }
    const float inv = 1.f / s;

    // spread attn back into 6x6 tap-weight field (reuse qk storage)
#pragma unroll
    for (int i = 0; i < 36; ++i) qk[i] = 0.f;
#pragma unroll
    for (int py = 0; py < 5; ++py)
#pragma unroll
        for (int px = 0; px < 5; ++px) {
            const float av = a[py * 5 + px] * inv;
            qk[py * 6 + px]           += av * wy0 * wx0;
            qk[py * 6 + px + 1]       += av * wy0 * wx1;
            qk[(py + 1) * 6 + px]     += av * wy1 * wx0;
            qk[(py + 1) * 6 + px + 1] += av * wy1 * wx1;
        }

    const float* v0p = v + ((size_t)b * Cc + ch0) * HW;
    const float* v1p = v0p + HW;
    float o0 = 0.f, o1 = 0.f;
#pragma unroll
    for (int r = 0; r < 6; ++r) {
        const int yr = by + r;
        const bool rv = (yr >= 0) & (yr < Hh);
        const int yc = min(max(yr, 0), Hh - 1);
#pragma unroll
        for (int c = 0; c < 6; ++c) {
            const int xc = bx + c;
            const bool cv = rv & (xc >= 0) & (xc < Ww);
            const int xcc = min(max(xc, 0), Ww - 1);
            const float m = cv ? 1.f : 0.f;
            const int off = yc * Ww + xcc;
            const float wv = qk[r * 6 + c] * m;
            o0 = fmaf(wv, v0p[off], o0);
            o1 = fmaf(wv, v1p[off], o1);
        }
    }
    out[((size_t)b * Cc + ch0) * HW + pix]     = o0;
    out[((size_t)b * Cc + ch0 + 1) * HW + pix] = o1;
}

// ---------------------------------------------------------------------------
// GroupNorm(1, C) finalize: y = (x - mean) * rsqrt(var+eps) * gamma + beta
// ---------------------------------------------------------------------------
__global__ void __launch_bounds__(256)
gn_k(const float* __restrict__ Y, const float* __restrict__ sums,
     const float* __restrict__ gamma, const float* __restrict__ beta,
     float* __restrict__ out)
{
    const float invN = 1.f / (float)(Cc * HW);
    const int qd  = blockIdx.x * blockDim.x + threadIdx.x;
    const int idx = qd * 4;
    const int b = idx / (Cc * HW);
    const int c = (idx % (Cc * HW)) / HW;
    const float mean = sums[b * 2] * invN;
    const float var  = fmaf(-mean, mean, sums[b * 2 + 1] * invN);
    const float rs = rsqrtf(var + 1e-5f);
    const float g  = gamma[c] * rs;
    const float be = beta[c];
    float4 yv = *(const float4*)&Y[idx];
    float4 ov;
    ov.x = fmaf(yv.x - mean, g, be);
    ov.y = fmaf(yv.y - mean, g, be);
    ov.z = fmaf(yv.z - mean, g, be);
    ov.w = fmaf(yv.w - mean, g, be);
    *(float4*)&out[idx] = ov;
}

// ---------------------------------------------------------------------------
extern "C" void kernel_launch(void* const* d_in, const int* in_sizes, int n_in,
                              void* d_out, int out_size, void* d_ws, size_t ws_size,
                              hipStream_t stream)
{
    const float* query  = (const float*)d_in[0];
    const float* key    = (const float*)d_in[1];
    const float* value  = (const float*)d_in[2];
    const float* deform = (const float*)d_in[3];
    const float* w_q    = (const float*)d_in[4];
    const float* w_k    = (const float*)d_in[5];
    const float* w_v    = (const float*)d_in[6];
    const float* w_fc   = (const float*)d_in[7];
    const float* mlp_w1 = (const float*)d_in[8];
    const float* mlp_b1 = (const float*)d_in[9];
    const float* mlp_w2 = (const float*)d_in[10];
    const float* mlp_b2 = (const float*)d_in[11];
    const float* gn_g   = (const float*)d_in[12];
    const float* gn_b   = (const float*)d_in[13];
    float* out = (float*)d_out;

    const size_t S = (size_t)Nn * Cc * HW;   // 2,359,296 floats
    float* ws  = (float*)d_ws;
    float* qb   = ws;           // q   -> later y1 (fc out)
    float* kb   = ws + S;       // k   -> later mlp hidden (2S: spans kb..vb)
    float* vb   = ws + 2 * S;   // v
    float* ab   = ws + 3 * S;   // attn_out -> later y2 (pre-GN)
    float* sums = ws + 4 * S;   // 4 floats: {sum,sumsq} x 2 batches

    hipMemsetAsync(sums, 0, 4 * sizeof(float), stream);

    dim3 blk(256);
    dim3 g128(HW / 128, 2, Nn);   // M=128 tiles
    dim3 g256(HW / 128, 4, Nn);   // M=256 tiles

    // q, k, v projections
    gemm_k<false, false, false, false><<<g128, blk, 0, stream>>>(
        w_q, query, nullptr, nullptr, qb, nullptr, 128, 128, HW);
    gemm_k<false, false, false, false><<<g128, blk, 0, stream>>>(
        w_k, key, nullptr, nullptr, kb, nullptr, 128, 128, HW);
    gemm_k<false, false, false, false><<<g128, blk, 0, stream>>>(
        w_v, value, nullptr, nullptr, vb, nullptr, 128, 128, HW);

    // deformable window attention (one wave per pixel)
    attn_kernel<<<dim3(Nn * HW / 4), blk, 0, stream>>>(qb, kb, vb, deform, ab);

    // fc: y1 = w_fc @ attn_out   (reuse q slot)
    gemm_k<false, false, false, false><<<g128, blk, 0, stream>>>(
        w_fc, ab, nullptr, nullptr, qb, nullptr, 128, 128, HW);

    // mlp hidden: h = lrelu(w1 @ y1 + b1)  (reuse k+v slots, M=256)
    gemm_k<true, true, false, false><<<g256, blk, 0, stream>>>(
        mlp_w1, qb, mlp_b1, nullptr, kb, nullptr, 256, 128, HW);

    // y2 = y1 + w2 @ h + b2, with per-batch sum/sumsq reduction (reuse attn slot)
    gemm_k<true, false, true, true><<<g128, blk, 0, stream>>>(
        mlp_w2, kb, mlp_b2, qb, ab, sums, 128, 256, HW);

    // GroupNorm finalize
    gn_k<<<dim3((unsigned)(S / 4 / 256)), blk, 0, stream>>>(ab, sums, gn_g, gn_b, out);
}

// Round 2
// 241.948 us; speedup vs baseline: 2.6625x; 2.6625x over previous
//
#include <hip/hip_runtime.h>
#include <cstddef>

// Problem constants (n=2, c=128, h=w=96, hid=256, P=5, heads=8, d_k=16)
constexpr int Cc = 128;
constexpr int Hh = 96;
constexpr int Ww = 96;
constexpr int HW = Hh * Ww;      // 9216 pixels per image
constexpr int Nn = 2;

// ---------------------------------------------------------------------------
// fp32 GEMM body over pixels. Tile: 32 oc x 128 pixels per 256-thread block
// (each thread 4 oc x 4 pix). K staged in 16-chunks in LDS.
// TOUT=false: Y[z][oc][pix] (NCHW).  TOUT=true: Y[z][pix][oc] (NHWC, M=Cc).
// Optional bias / leaky-relu / residual-add / per-batch sum&sumsq reduction.
// ---------------------------------------------------------------------------
template<bool BIAS, bool LRELU, bool RESID, bool REDUCE, bool TOUT>
__device__ __forceinline__ void gemm_body(
    const float* __restrict__ Wm, const float* __restrict__ X,
    const float* __restrict__ bias, const float* __restrict__ resid,
    float* __restrict__ Y, float* __restrict__ sums,
    int M, int K, int z, int m0, int p0)
{
    __shared__ float wlds[16 * 36];    // [k][oc], stride 36 kills bank conflicts
    __shared__ float xlds[16 * 128];   // [k][pix]
    __shared__ float red[8];

    const int tid = threadIdx.x;
    const int tx = tid & 31;   // pixel quad: pixels p0 + tx*4 .. +3
    const int ty = tid >> 5;   // oc quad:    oc   m0 + ty*4 .. +3
    const float* Xz = X + (size_t)z * K * HW;

    float acc[4][4];
#pragma unroll
    for (int o = 0; o < 4; ++o)
#pragma unroll
        for (int j = 0; j < 4; ++j) acc[o][j] = 0.f;

    const int wrow = tid >> 3;         // 0..31 (oc within tile)
    const int wk   = (tid & 7) * 2;    // 0,2,..,14 (k within chunk)

    for (int k0 = 0; k0 < K; k0 += 16) {
        float2 wv  = *(const float2*)&Wm[(size_t)(m0 + wrow) * K + k0 + wk];
        float4 xv0 = *(const float4*)&Xz[(size_t)(k0 + ty) * HW + p0 + tx * 4];
        float4 xv1 = *(const float4*)&Xz[(size_t)(k0 + 8 + ty) * HW + p0 + tx * 4];
        __syncthreads();
        wlds[(wk + 0) * 36 + wrow] = wv.x;
        wlds[(wk + 1) * 36 + wrow] = wv.y;
        *(float4*)&xlds[ty * 128 + tx * 4]       = xv0;
        *(float4*)&xlds[(ty + 8) * 128 + tx * 4] = xv1;
        __syncthreads();
#pragma unroll
        for (int kk = 0; kk < 16; ++kk) {
            float4 xv = *(float4*)&xlds[kk * 128 + tx * 4];
            float4 wf = *(float4*)&wlds[kk * 36 + ty * 4];   // broadcast (2 addrs/wave)
            float wr[4] = {wf.x, wf.y, wf.z, wf.w};
#pragma unroll
            for (int o = 0; o < 4; ++o) {
                acc[o][0] = fmaf(wr[o], xv.x, acc[o][0]);
                acc[o][1] = fmaf(wr[o], xv.y, acc[o][1]);
                acc[o][2] = fmaf(wr[o], xv.z, acc[o][2]);
                acc[o][3] = fmaf(wr[o], xv.w, acc[o][3]);
            }
        }
    }

    if (TOUT) {
        // NHWC store: for each pixel, 4 consecutive channels -> one float4
#pragma unroll
        for (int j = 0; j < 4; ++j) {
            float4 ov = make_float4(acc[0][j], acc[1][j], acc[2][j], acc[3][j]);
            *(float4*)&Y[((size_t)z * HW + p0 + tx * 4 + j) * Cc + m0 + ty * 4] = ov;
        }
    } else {
        float lsum = 0.f, lsq = 0.f;
#pragma unroll
        for (int o = 0; o < 4; ++o) {
            const int oc = m0 + ty * 4 + o;
            float t0 = acc[o][0], t1 = acc[o][1], t2 = acc[o][2], t3 = acc[o][3];
            if (BIAS) {
                float bv = bias[oc];
                t0 += bv; t1 += bv; t2 += bv; t3 += bv;
            }
            if (LRELU) {
                t0 = t0 >= 0.f ? t0 : 0.2f * t0;
                t1 = t1 >= 0.f ? t1 : 0.2f * t1;
                t2 = t2 >= 0.f ? t2 : 0.2f * t2;
                t3 = t3 >= 0.f ? t3 : 0.2f * t3;
            }
            if (RESID) {
                float4 rv = *(const float4*)&resid[((size_t)z * M + oc) * HW + p0 + tx * 4];
                t0 += rv.x; t1 += rv.y; t2 += rv.z; t3 += rv.w;
            }
            if (REDUCE) {
                lsum += t0 + t1 + t2 + t3;
                lsq  += t0 * t0 + t1 * t1 + t2 * t2 + t3 * t3;
            }
            *(float4*)&Y[((size_t)z * M + oc) * HW + p0 + tx * 4] =
                make_float4(t0, t1, t2, t3);
        }
        if (REDUCE) {
#pragma unroll
            for (int m = 1; m < 64; m <<= 1) {
                lsum += __shfl_xor(lsum, m, 64);
                lsq  += __shfl_xor(lsq,  m, 64);
            }
            if ((tid & 63) == 0) {
                red[(tid >> 6) * 2]     = lsum;
                red[(tid >> 6) * 2 + 1] = lsq;
            }
            __syncthreads();
            if (tid == 0) {
                atomicAdd(&sums[z * 2 + 0], red[0] + red[2] + red[4] + red[6]);
                atomicAdd(&sums[z * 2 + 1], red[1] + red[3] + red[5] + red[7]);
            }
        }
    }
}

template<bool BIAS, bool LRELU, bool RESID, bool REDUCE, bool TOUT>
__global__ void __launch_bounds__(256)
gemm_k(const float* __restrict__ Wm, const float* __restrict__ X,
       const float* __restrict__ bias, const float* __restrict__ resid,
       float* __restrict__ Y, float* __restrict__ sums, int M, int K)
{
    gemm_body<BIAS, LRELU, RESID, REDUCE, TOUT>(
        Wm, X, bias, resid, Y, sums, M, K,
        blockIdx.z, blockIdx.y * 32, blockIdx.x * 128);
}

// Fused q/k/v projections in one dispatch (3x the resident blocks).
// grid (72, 12, 2): blockIdx.y: tensor = y>>2, m0 = (y&3)*32.
__global__ void __launch_bounds__(256)
qkv_k(const float* __restrict__ Wq, const float* __restrict__ Wk,
      const float* __restrict__ Wv, const float* __restrict__ Xq,
      const float* __restrict__ Xk, const float* __restrict__ Xv,
      float* __restrict__ Yq, float* __restrict__ Yk, float* __restrict__ Yv)
{
    const int t = blockIdx.y >> 2;
    const float* Wm = (t == 0) ? Wq : (t == 1) ? Wk : Wv;
    const float* X  = (t == 0) ? Xq : (t == 1) ? Xk : Xv;
    float* Y        = (t == 0) ? Yq : (t == 1) ? Yk : Yv;
    gemm_body<false, false, false, false, true>(
        Wm, X, nullptr, nullptr, Y, nullptr, Cc, Cc,
        blockIdx.z, (blockIdx.y & 3) * 32, blockIdx.x * 128);
}

// ---------------------------------------------------------------------------
// Deformable window attention, one wave per pixel. q/k/v are NHWC
// ([b][pix][128]), so every patch-position load is one coalesced 512 B wave
// transaction (lane owns channels 2*lane, 2*lane+1; head = lane>>3).
// All 25 samples share fractional weights; corners live in a 6x6 patch.
// Output written NCHW for the downstream fc GEMM.
// Blocks are band-swizzled so each XCD's L2 sees a contiguous ~24-row band.
// ---------------------------------------------------------------------------
__global__ void __launch_bounds__(256)
attn_kernel(const float* __restrict__ q, const float* __restrict__ k,
            const float* __restrict__ v, const float* __restrict__ df,
            float* __restrict__ out)
{
    const int blk = blockIdx.x;
    const int nb8 = gridDim.x >> 3;
    const int sw  = (blk & 7) * nb8 + (blk >> 3);    // XCD band swizzle
    const int wid  = sw * 4 + (threadIdx.x >> 6);
    const int lane = threadIdx.x & 63;
    const int b = wid / HW;
    const int pix = wid % HW;
    const int y = pix / Ww;
    const int x = pix % Ww;
    const int ch0 = lane * 2;

    const float dx = df[((size_t)b * 2 + 0) * HW + pix];
    const float dy = df[((size_t)b * 2 + 1) * HW + pix];
    const float flx = floorf(dx), fly = floorf(dy);
    const int bx = x - 2 + (int)flx;
    const int by = y - 2 + (int)fly;
    const float wx1 = dx - flx, wx0 = 1.f - wx1;
    const float wy1 = dy - fly, wy0 = 1.f - wy1;

    const float2 qv = *(const float2*)&q[((size_t)b * HW + pix) * Cc + ch0];
    const float qs0 = qv.x * 0.25f;   // 1/sqrt(d_k)=0.25
    const float qs1 = qv.y * 0.25f;

    const float* kb = k + (size_t)b * HW * Cc;
    const float* vb = v + (size_t)b * HW * Cc;

    float qk[36];
#pragma unroll
    for (int r = 0; r < 6; ++r) {
        const int yr = by + r;
        const bool rv = (yr >= 0) & (yr < Hh);
        const int yc = min(max(yr, 0), Hh - 1);
#pragma unroll
        for (int c = 0; c < 6; ++c) {
            const int xc = bx + c;
            const bool cv = rv & (xc >= 0) & (xc < Ww);
            const int xcc = min(max(xc, 0), Ww - 1);
            const float m = cv ? 1.f : 0.f;
            const float2 kv = *(const float2*)&kb[(size_t)(yc * Ww + xcc) * Cc + ch0];
            qk[r * 6 + c] = (qs0 * kv.x + qs1 * kv.y) * m;
        }
    }
    // reduce partial qk over the 8 slots of this head
#pragma unroll
    for (int m = 1; m <= 4; m <<= 1) {
#pragma unroll
        for (int i = 0; i < 36; ++i)
            qk[i] += __shfl_xor(qk[i], m, 64);
    }

    // logits + max
    float a[25];
    float mx = -1e30f;
#pragma unroll
    for (int py = 0; py < 5; ++py)
#pragma unroll
        for (int px = 0; px < 5; ++px) {
            float t = wy0 * (wx0 * qk[py * 6 + px]       + wx1 * qk[py * 6 + px + 1])
                    + wy1 * (wx0 * qk[(py + 1) * 6 + px] + wx1 * qk[(py + 1) * 6 + px + 1]);
            a[py * 5 + px] = t;
            mx = fmaxf(mx, t);
        }
    float s = 0.f;
#pragma unroll
    for (int i = 0; i < 25; ++i) { a[i] = __expf(a[i] - mx); s += a[i]; }
    const float inv = 1.f / s;

    // spread attn back into 6x6 tap-weight field (reuse qk storage)
#pragma unroll
    for (int i = 0; i < 36; ++i) qk[i] = 0.f;
#pragma unroll
    for (int py = 0; py < 5; ++py)
#pragma unroll
        for (int px = 0; px < 5; ++px) {
            const float av = a[py * 5 + px] * inv;
            qk[py * 6 + px]           += av * wy0 * wx0;
            qk[py * 6 + px + 1]       += av * wy0 * wx1;
            qk[(py + 1) * 6 + px]     += av * wy1 * wx0;
            qk[(py + 1) * 6 + px + 1] += av * wy1 * wx1;
        }

    float o0 = 0.f, o1 = 0.f;
#pragma unroll
    for (int r = 0; r < 6; ++r) {
        const int yr = by + r;
        const bool rv = (yr >= 0) & (yr < Hh);
        const int yc = min(max(yr, 0), Hh - 1);
#pragma unroll
        for (int c = 0; c < 6; ++c) {
            const int xc = bx + c;
            const bool cv = rv & (xc >= 0) & (xc < Ww);
            const int xcc = min(max(xc, 0), Ww - 1);
            const float m = cv ? 1.f : 0.f;
            const float2 vv = *(const float2*)&vb[(size_t)(yc * Ww + xcc) * Cc + ch0];
            const float wv = qk[r * 6 + c] * m;
            o0 = fmaf(wv, vv.x, o0);
            o1 = fmaf(wv, vv.y, o1);
        }
    }
    out[((size_t)b * Cc + ch0) * HW + pix]     = o0;
    out[((size_t)b * Cc + ch0 + 1) * HW + pix] = o1;
}

// ---------------------------------------------------------------------------
// GroupNorm(1, C) finalize: y = (x - mean) * rsqrt(var+eps) * gamma + beta
// ---------------------------------------------------------------------------
__global__ void __launch_bounds__(256)
gn_k(const float* __restrict__ Y, const float* __restrict__ sums,
     const float* __restrict__ gamma, const float* __restrict__ beta,
     float* __restrict__ out)
{
    const float invN = 1.f / (float)(Cc * HW);
    const int qd  = blockIdx.x * blockDim.x + threadIdx.x;
    const int idx = qd * 4;
    const int b = idx / (Cc * HW);
    const int c = (idx % (Cc * HW)) / HW;
    const float mean = sums[b * 2] * invN;
    const float var  = fmaf(-mean, mean, sums[b * 2 + 1] * invN);
    const float rs = rsqrtf(var + 1e-5f);
    const float g  = gamma[c] * rs;
    const float be = beta[c];
    float4 yv = *(const float4*)&Y[idx];
    float4 ov;
    ov.x = fmaf(yv.x - mean, g, be);
    ov.y = fmaf(yv.y - mean, g, be);
    ov.z = fmaf(yv.z - mean, g, be);
    ov.w = fmaf(yv.w - mean, g, be);
    *(float4*)&out[idx] = ov;
}

// ---------------------------------------------------------------------------
extern "C" void kernel_launch(void* const* d_in, const int* in_sizes, int n_in,
                              void* d_out, int out_size, void* d_ws, size_t ws_size,
                              hipStream_t stream)
{
    const float* query  = (const float*)d_in[0];
    const float* key    = (const float*)d_in[1];
    const float* value  = (const float*)d_in[2];
    const float* deform = (const float*)d_in[3];
    const float* w_q    = (const float*)d_in[4];
    const float* w_k    = (const float*)d_in[5];
    const float* w_v    = (const float*)d_in[6];
    const float* w_fc   = (const float*)d_in[7];
    const float* mlp_w1 = (const float*)d_in[8];
    const float* mlp_b1 = (const float*)d_in[9];
    const float* mlp_w2 = (const float*)d_in[10];
    const float* mlp_b2 = (const float*)d_in[11];
    const float* gn_g   = (const float*)d_in[12];
    const float* gn_b   = (const float*)d_in[13];
    float* out = (float*)d_out;

    const size_t S = (size_t)Nn * Cc * HW;   // 2,359,296 floats
    float* ws  = (float*)d_ws;
    float* qb   = ws;           // q (NHWC) -> later y1 (fc out, NCHW)
    float* kb   = ws + S;       // k (NHWC) -> later mlp hidden (spans kb..vb)
    float* vb   = ws + 2 * S;   // v (NHWC)
    float* ab   = ws + 3 * S;   // attn_out (NCHW) -> later y2 (pre-GN)
    float* sums = ws + 4 * S;   // 4 floats: {sum,sumsq} x 2 batches

    hipMemsetAsync(sums, 0, 4 * sizeof(float), stream);

    dim3 blk(256);

    // fused q, k, v projections -> NHWC
    qkv_k<<<dim3(HW / 128, 12, Nn), blk, 0, stream>>>(
        w_q, w_k, w_v, query, key, value, qb, kb, vb);

    // deformable window attention (one wave per pixel) -> NCHW
    attn_kernel<<<dim3(Nn * HW / 4), blk, 0, stream>>>(qb, kb, vb, deform, ab);

    // fc: y1 = w_fc @ attn_out
    gemm_k<false, false, false, false, false><<<dim3(HW / 128, 4, Nn), blk, 0, stream>>>(
        w_fc, ab, nullptr, nullptr, qb, nullptr, 128, 128);

    // mlp hidden: h = lrelu(w1 @ y1 + b1)
    gemm_k<true, true, false, false, false><<<dim3(HW / 128, 8, Nn), blk, 0, stream>>>(
        mlp_w1, qb, mlp_b1, nullptr, kb, nullptr, 256, 128);

    // y2 = y1 + w2 @ h + b2, with per-batch sum/sumsq reduction
    gemm_k<true, false, true, true, false><<<dim3(HW / 128, 4, Nn), blk, 0, stream>>>(
        mlp_w2, kb, mlp_b2, qb, ab, sums, 128, 256);

    // GroupNorm finalize
    gn_k<<<dim3((unsigned)(S / 4 / 256)), blk, 0, stream>>>(ab, sums, gn_g, gn_b, out);
}

// Round 3
// 196.713 us; speedup vs baseline: 3.2748x; 1.2300x over previous
//
#include <hip/hip_runtime.h>
#include <cstddef>

// Problem constants (n=2, c=128, h=w=96, hid=256, P=5, heads=8, d_k=16)
constexpr int Cc = 128;
constexpr int Hh = 96;
constexpr int Ww = 96;
constexpr int HW = Hh * Ww;      // 9216 pixels per image
constexpr int Nn = 2;

typedef __attribute__((ext_vector_type(4))) float f32x4;
typedef __attribute__((ext_vector_type(8))) short sh8;
typedef __attribute__((ext_vector_type(4))) short sh4;

__device__ __forceinline__ short f2bf(float f) {
    union { float f; unsigned u; } c; c.f = f;
    unsigned r = c.u + 0x7FFF + ((c.u >> 16) & 1);   // round-to-nearest-even
    return (short)(r >> 16);
}

// ---------------------------------------------------------------------------
// bf16 MFMA GEMM body. Y[z][m][p] = sum_k W[m][k] * X[z][k][p], X NCHW fp32.
// Tile: (NHWC ? 128 : 64) output-channels x 128 pixels, K chunked by 128.
// X staged fragment-major in LDS (each lane's 8 k-elems contiguous);
// W staged as bf16 rows (k-contiguous natively).
// NHWC=true: A=X^T (D rows = pixels) -> Y[z][p][Cc] coalesced stores (qkv).
// NHWC=false: A=W (D rows = channels) -> Y[z][m][p] coalesced stores.
// ---------------------------------------------------------------------------
template<int WROWS, bool NHWC, bool BIAS, bool LRELU, bool RESID, bool REDUCE>
__device__ __forceinline__ void mgemm_body(
    const float* __restrict__ Wm, const float* __restrict__ X,
    const float* __restrict__ bias, const float* __restrict__ resid,
    float* __restrict__ Y, float* __restrict__ sums,
    int M, int K, int z, int m0, int p0)
{
    __shared__ __align__(16) short xf[4 * 128 * 40];     // [ks][p][quad*8 + pad]
    __shared__ __align__(16) short wf[WROWS * 136];      // [row][k + 8 pad]
    __shared__ float red[8];

    const int tid  = threadIdx.x;
    const int w    = tid >> 6;
    const int lane = tid & 63;
    const int n16  = lane & 15;
    const int quad = lane >> 4;
    const float* Xz = X + (size_t)z * K * HW + p0;

    constexpr int MI = NHWC ? 4 : 2;
    f32x4 acc[MI][4];
#pragma unroll
    for (int mi = 0; mi < MI; ++mi)
#pragma unroll
        for (int ni = 0; ni < 4; ++ni) acc[mi][ni] = (f32x4)0.f;

    const int sp = tid & 127;     // pixel for X staging
    const int sq = tid >> 7;      // 0..1

    for (int kc = 0; kc < K; kc += 128) {
        if (kc > 0) __syncthreads();
        // ---- stage X chunk fragment-major ----
#pragma unroll
        for (int s = 0; s < 8; ++s) {
            const int c  = s * 2 + sq;      // 0..15
            const int ks = c >> 2, q = c & 3;
            const int kbase = kc + ks * 32 + q * 8;
            sh8 pk;
#pragma unroll
            for (int j = 0; j < 8; ++j)
                pk[j] = f2bf(Xz[(size_t)(kbase + j) * HW + sp]);
            *(sh8*)&xf[(ks * 128 + sp) * 40 + q * 8] = pk;
        }
        // ---- stage W chunk rows ----
#pragma unroll
        for (int i = 0; i < WROWS / 8; ++i) {
            const int idx = i * 256 + tid;
            const int row = idx >> 5, c4 = idx & 31;
            float4 wv = *(const float4*)&Wm[(size_t)(m0 + row) * K + kc + c4 * 4];
            sh4 pw;
            pw[0] = f2bf(wv.x); pw[1] = f2bf(wv.y);
            pw[2] = f2bf(wv.z); pw[3] = f2bf(wv.w);
            *(sh4*)&wf[row * 136 + c4 * 4] = pw;
        }
        __syncthreads();
        // ---- MFMA over this chunk ----
#pragma unroll
        for (int ks = 0; ks < 4; ++ks) {
            sh8 af[MI], bf[4];
            if (NHWC) {
#pragma unroll
                for (int mi = 0; mi < MI; ++mi) {   // A = X^T : rows = pixels
                    const int pl = (w & 1) * 64 + mi * 16 + n16;
                    af[mi] = *(const sh8*)&xf[(ks * 128 + pl) * 40 + quad * 8];
                }
#pragma unroll
                for (int ni = 0; ni < 4; ++ni) {    // B = W^T : cols = channels
                    const int row = (w >> 1) * 64 + ni * 16 + n16;
                    bf[ni] = *(const sh8*)&wf[row * 136 + ks * 32 + quad * 8];
                }
            } else {
#pragma unroll
                for (int mi = 0; mi < MI; ++mi) {   // A = W : rows = channels
                    const int row = (w & 1) * 32 + mi * 16 + n16;
                    af[mi] = *(const sh8*)&wf[row * 136 + ks * 32 + quad * 8];
                }
#pragma unroll
                for (int ni = 0; ni < 4; ++ni) {    // B = X : cols = pixels
                    const int pl = (w >> 1) * 64 + ni * 16 + n16;
                    bf[ni] = *(const sh8*)&xf[(ks * 128 + pl) * 40 + quad * 8];
                }
            }
#pragma unroll
            for (int mi = 0; mi < MI; ++mi)
#pragma unroll
                for (int ni = 0; ni < 4; ++ni)
                    acc[mi][ni] = __builtin_amdgcn_mfma_f32_16x16x32_bf16(
                        af[mi], bf[ni], acc[mi][ni], 0, 0, 0);
        }
    }

    // ---- epilogue ----
    if (NHWC) {
        // D[m=pixel][n=channel] -> Y[z][pix][Cc]
#pragma unroll
        for (int mi = 0; mi < MI; ++mi)
#pragma unroll
            for (int r = 0; r < 4; ++r) {
                const int pix = p0 + (w & 1) * 64 + mi * 16 + quad * 4 + r;
#pragma unroll
                for (int ni = 0; ni < 4; ++ni) {
                    const int ch = (w >> 1) * 64 + ni * 16 + n16;
                    Y[((size_t)z * HW + pix) * Cc + ch] = acc[mi][ni][r];
                }
            }
    } else {
        float lsum = 0.f, lsq = 0.f;
#pragma unroll
        for (int mi = 0; mi < MI; ++mi)
#pragma unroll
            for (int r = 0; r < 4; ++r) {
                const int ch = m0 + (w & 1) * 32 + mi * 16 + quad * 4 + r;
                const float bv = BIAS ? bias[ch] : 0.f;
#pragma unroll
                for (int ni = 0; ni < 4; ++ni) {
                    const int p = p0 + (w >> 1) * 64 + ni * 16 + n16;
                    float t = acc[mi][ni][r] + bv;
                    if (LRELU) t = t >= 0.f ? t : 0.2f * t;
                    if (RESID) t += resid[((size_t)z * M + ch) * HW + p];
                    if (REDUCE) { lsum += t; lsq += t * t; }
                    Y[((size_t)z * M + ch) * HW + p] = t;
                }
            }
        if (REDUCE) {
#pragma unroll
            for (int m = 1; m < 64; m <<= 1) {
                lsum += __shfl_xor(lsum, m, 64);
                lsq  += __shfl_xor(lsq,  m, 64);
            }
            if (lane == 0) { red[w * 2] = lsum; red[w * 2 + 1] = lsq; }
            __syncthreads();
            if (tid == 0) {
                atomicAdd(&sums[z * 2 + 0], red[0] + red[2] + red[4] + red[6]);
                atomicAdd(&sums[z * 2 + 1], red[1] + red[3] + red[5] + red[7]);
            }
        }
    }
}

template<bool BIAS, bool LRELU, bool RESID, bool REDUCE>
__global__ void __launch_bounds__(256)
mg_k(const float* __restrict__ Wm, const float* __restrict__ X,
     const float* __restrict__ bias, const float* __restrict__ resid,
     float* __restrict__ Y, float* __restrict__ sums, int M, int K)
{
    mgemm_body<64, false, BIAS, LRELU, RESID, REDUCE>(
        Wm, X, bias, resid, Y, sums, M, K,
        blockIdx.z, blockIdx.y * 64, blockIdx.x * 128);
}

// Fused q/k/v projections -> NHWC fp32. grid (72, 3, 2), y = tensor.
__global__ void __launch_bounds__(256)
qkv_k(const float* __restrict__ Wq, const float* __restrict__ Wk,
      const float* __restrict__ Wv, const float* __restrict__ Xq,
      const float* __restrict__ Xk, const float* __restrict__ Xv,
      float* __restrict__ Yq, float* __restrict__ Yk, float* __restrict__ Yv)
{
    const int t = blockIdx.y;
    const float* Wm = (t == 0) ? Wq : (t == 1) ? Wk : Wv;
    const float* X  = (t == 0) ? Xq : (t == 1) ? Xk : Xv;
    float* Y        = (t == 0) ? Yq : (t == 1) ? Yk : Yv;
    mgemm_body<128, true, false, false, false, false>(
        Wm, X, nullptr, nullptr, Y, nullptr, Cc, Cc,
        blockIdx.z, 0, blockIdx.x * 128);
}

// ---------------------------------------------------------------------------
// Deformable window attention, one wave per pixel (unchanged from round 2).
// ---------------------------------------------------------------------------
__global__ void __launch_bounds__(256)
attn_kernel(const float* __restrict__ q, const float* __restrict__ k,
            const float* __restrict__ v, const float* __restrict__ df,
            float* __restrict__ out)
{
    const int blk = blockIdx.x;
    const int nb8 = gridDim.x >> 3;
    const int sw  = (blk & 7) * nb8 + (blk >> 3);    // XCD band swizzle
    const int wid  = sw * 4 + (threadIdx.x >> 6);
    const int lane = threadIdx.x & 63;
    const int b = wid / HW;
    const int pix = wid % HW;
    const int y = pix / Ww;
    const int x = pix % Ww;
    const int ch0 = lane * 2;

    const float dx = df[((size_t)b * 2 + 0) * HW + pix];
    const float dy = df[((size_t)b * 2 + 1) * HW + pix];
    const float flx = floorf(dx), fly = floorf(dy);
    const int bx = x - 2 + (int)flx;
    const int by = y - 2 + (int)fly;
    const float wx1 = dx - flx, wx0 = 1.f - wx1;
    const float wy1 = dy - fly, wy0 = 1.f - wy1;

    const float2 qv = *(const float2*)&q[((size_t)b * HW + pix) * Cc + ch0];
    const float qs0 = qv.x * 0.25f;   // 1/sqrt(d_k)=0.25
    const float qs1 = qv.y * 0.25f;

    const float* kb = k + (size_t)b * HW * Cc;
    const float* vb = v + (size_t)b * HW * Cc;

    float qk[36];
#pragma unroll
    for (int r = 0; r < 6; ++r) {
        const int yr = by + r;
        const bool rv = (yr >= 0) & (yr < Hh);
        const int yc = min(max(yr, 0), Hh - 1);
#pragma unroll
        for (int c = 0; c < 6; ++c) {
            const int xc = bx + c;
            const bool cv = rv & (xc >= 0) & (xc < Ww);
            const int xcc = min(max(xc, 0), Ww - 1);
            const float m = cv ? 1.f : 0.f;
            const float2 kv = *(const float2*)&kb[(size_t)(yc * Ww + xcc) * Cc + ch0];
            qk[r * 6 + c] = (qs0 * kv.x + qs1 * kv.y) * m;
        }
    }
#pragma unroll
    for (int m = 1; m <= 4; m <<= 1) {
#pragma unroll
        for (int i = 0; i < 36; ++i)
            qk[i] += __shfl_xor(qk[i], m, 64);
    }

    float a[25];
    float mx = -1e30f;
#pragma unroll
    for (int py = 0; py < 5; ++py)
#pragma unroll
        for (int px = 0; px < 5; ++px) {
            float t = wy0 * (wx0 * qk[py * 6 + px]       + wx1 * qk[py * 6 + px + 1])
                    + wy1 * (wx0 * qk[(py + 1) * 6 + px] + wx1 * qk[(py + 1) * 6 + px + 1]);
            a[py * 5 + px] = t;
            mx = fmaxf(mx, t);
        }
    float s = 0.f;
#pragma unroll
    for (int i = 0; i < 25; ++i) { a[i] = __expf(a[i] - mx); s += a[i]; }
    const float inv = 1.f / s;

#pragma unroll
    for (int i = 0; i < 36; ++i) qk[i] = 0.f;
#pragma unroll
    for (int py = 0; py < 5; ++py)
#pragma unroll
        for (int px = 0; px < 5; ++px) {
            const float av = a[py * 5 + px] * inv;
            qk[py * 6 + px]           += av * wy0 * wx0;
            qk[py * 6 + px + 1]       += av * wy0 * wx1;
            qk[(py + 1) * 6 + px]     += av * wy1 * wx0;
            qk[(py + 1) * 6 + px + 1] += av * wy1 * wx1;
        }

    float o0 = 0.f, o1 = 0.f;
#pragma unroll
    for (int r = 0; r < 6; ++r) {
        const int yr = by + r;
        const bool rv = (yr >= 0) & (yr < Hh);
        const int yc = min(max(yr, 0), Hh - 1);
#pragma unroll
        for (int c = 0; c < 6; ++c) {
            const int xc = bx + c;
            const bool cv = rv & (xc >= 0) & (xc < Ww);
            const int xcc = min(max(xc, 0), Ww - 1);
            const float m = cv ? 1.f : 0.f;
            const float2 vv = *(const float2*)&vb[(size_t)(yc * Ww + xcc) * Cc + ch0];
            const float wv = qk[r * 6 + c] * m;
            o0 = fmaf(wv, vv.x, o0);
            o1 = fmaf(wv, vv.y, o1);
        }
    }
    out[((size_t)b * Cc + ch0) * HW + pix]     = o0;
    out[((size_t)b * Cc + ch0 + 1) * HW + pix] = o1;
}

// ---------------------------------------------------------------------------
// GroupNorm(1, C) finalize
// ---------------------------------------------------------------------------
__global__ void __launch_bounds__(256)
gn_k(const float* __restrict__ Y, const float* __restrict__ sums,
     const float* __restrict__ gamma, const float* __restrict__ beta,
     float* __restrict__ out)
{
    const float invN = 1.f / (float)(Cc * HW);
    const int qd  = blockIdx.x * blockDim.x + threadIdx.x;
    const int idx = qd * 4;
    const int b = idx / (Cc * HW);
    const int c = (idx % (Cc * HW)) / HW;
    const float mean = sums[b * 2] * invN;
    const float var  = fmaf(-mean, mean, sums[b * 2 + 1] * invN);
    const float rs = rsqrtf(var + 1e-5f);
    const float g  = gamma[c] * rs;
    const float be = beta[c];
    float4 yv = *(const float4*)&Y[idx];
    float4 ov;
    ov.x = fmaf(yv.x - mean, g, be);
    ov.y = fmaf(yv.y - mean, g, be);
    ov.z = fmaf(yv.z - mean, g, be);
    ov.w = fmaf(yv.w - mean, g, be);
    *(float4*)&out[idx] = ov;
}

// ---------------------------------------------------------------------------
extern "C" void kernel_launch(void* const* d_in, const int* in_sizes, int n_in,
                              void* d_out, int out_size, void* d_ws, size_t ws_size,
                              hipStream_t stream)
{
    const float* query  = (const float*)d_in[0];
    const float* key    = (const float*)d_in[1];
    const float* value  = (const float*)d_in[2];
    const float* deform = (const float*)d_in[3];
    const float* w_q    = (const float*)d_in[4];
    const float* w_k    = (const float*)d_in[5];
    const float* w_v    = (const float*)d_in[6];
    const float* w_fc   = (const float*)d_in[7];
    const float* mlp_w1 = (const float*)d_in[8];
    const float* mlp_b1 = (const float*)d_in[9];
    const float* mlp_w2 = (const float*)d_in[10];
    const float* mlp_b2 = (const float*)d_in[11];
    const float* gn_g   = (const float*)d_in[12];
    const float* gn_b   = (const float*)d_in[13];
    float* out = (float*)d_out;

    const size_t S = (size_t)Nn * Cc * HW;   // 2,359,296 floats
    float* ws  = (float*)d_ws;
    float* qb   = ws;           // q (NHWC) -> later y1 (fc out, NCHW)
    float* kb   = ws + S;       // k (NHWC) -> later mlp hidden (spans kb..vb)
    float* vb   = ws + 2 * S;   // v (NHWC)
    float* ab   = ws + 3 * S;   // attn_out (NCHW) -> later y2 (pre-GN)
    float* sums = ws + 4 * S;   // 4 floats: {sum,sumsq} x 2 batches

    hipMemsetAsync(sums, 0, 4 * sizeof(float), stream);

    dim3 blk(256);

    // fused q, k, v projections -> NHWC fp32 (bf16 MFMA)
    qkv_k<<<dim3(HW / 128, 3, Nn), blk, 0, stream>>>(
        w_q, w_k, w_v, query, key, value, qb, kb, vb);

    // deformable window attention (one wave per pixel) -> NCHW
    attn_kernel<<<dim3(Nn * HW / 4), blk, 0, stream>>>(qb, kb, vb, deform, ab);

    // fc: y1 = w_fc @ attn_out
    mg_k<false, false, false, false><<<dim3(HW / 128, 2, Nn), blk, 0, stream>>>(
        w_fc, ab, nullptr, nullptr, qb, nullptr, 128, 128);

    // mlp hidden: h = lrelu(w1 @ y1 + b1)
    mg_k<true, true, false, false><<<dim3(HW / 128, 4, Nn), blk, 0, stream>>>(
        mlp_w1, qb, mlp_b1, nullptr, kb, nullptr, 256, 128);

    // y2 = y1 + w2 @ h + b2, with per-batch sum/sumsq reduction
    mg_k<true, false, true, true><<<dim3(HW / 128, 2, Nn), blk, 0, stream>>>(
        mlp_w2, kb, mlp_b2, qb, ab, sums, 128, 256);

    // GroupNorm finalize
    gn_k<<<dim3((unsigned)(S / 4 / 256)), blk, 0, stream>>>(ab, sums, gn_g, gn_b, out);
}